// Round 16
// baseline (297.517 us; speedup 1.0000x reference)
//
#include <hip/hip_runtime.h>

// GAT encoder, 3 layers. N=50000, E=800000, Fin=128.
// R15 -> R16: aggr batch depth doubled (UN 4->8 for FOUT=128, 2->4 for
// FOUT=64). With UN=4 a group ran E[ceil(gc/4)]~1.4 dependent-latency rounds
// (gc ~ Poisson(17)/GROUPS); UN=8 makes nearly every group single-round with
// 32 rows in flight per wave. Predicated slots contribute exactly 0.0f ->
// bit-identical output (absmax 0.001953125). Everything else R15 verbatim.

#define NEG_SLOPE 0.2f

typedef _Float16 f16;
typedef f16 f16x8 __attribute__((ext_vector_type(8)));
typedef f16 f16x4 __attribute__((ext_vector_type(4)));
typedef f16 f16x2 __attribute__((ext_vector_type(2)));
typedef float f32x4 __attribute__((ext_vector_type(4)));

#define BSH 6                    // coarse bucket = dst >> BSH
#define DLOWM 63                 // dlow mask (6 bits)
#define KEYBITS 22               // 6-bit dlow + 16-bit src
#define CNTB 196                 // count blocks appended to gemm0

__device__ __forceinline__ float lrelu(float v) { return v > 0.f ? v : NEG_SLOPE * v; }

// ---------------- CSR build pieces ----------------

// Exclusive scan of NBK bucket counts; seeds bcursor; offsets[N]=E.
__global__ __launch_bounds__(256) void bucket_scan_kernel(const int* __restrict__ bcount, int NBK,
                                                          int* __restrict__ bbase,
                                                          int* __restrict__ bcursor,
                                                          int* __restrict__ offsets, int N) {
    int t = threadIdx.x;
    int chunk = (NBK + 255) / 256;
    int b0 = t * chunk, b1 = b0 + chunk;
    if (b0 > NBK) b0 = NBK;
    if (b1 > NBK) b1 = NBK;
    int s = 0;
    for (int i = b0; i < b1; ++i) s += bcount[i];
    int v = s;
    int lane = t & 63, wid = t >> 6;
#pragma unroll
    for (int off = 1; off < 64; off <<= 1) {
        int u = __shfl_up(v, off);
        if (lane >= off) v += u;
    }
    __shared__ int ws[4];
    if (lane == 63) ws[wid] = v;
    __syncthreads();
    int add = 0;
    for (int w = 0; w < wid; ++w) add += ws[w];
    v += add;
    int prefix = v - s;
    for (int i = b0; i < b1; ++i) {
        bbase[i] = prefix;
        bcursor[i] = prefix;
        prefix += bcount[i];
    }
    if (t == 255) {
        bbase[NBK] = v;
        offsets[N] = v;
    }
}

#define SC_TILE 4096
__global__ __launch_bounds__(256) void bucket_scatter_kernel(const int* __restrict__ src,
                                                             const int* __restrict__ dst, int E,
                                                             int* __restrict__ bcursor,
                                                             unsigned int* __restrict__ staging) {
    __shared__ int lh[1024];
    __shared__ int lcur[1024];
    int tid = threadIdx.x;
#pragma unroll
    for (int j = 0; j < 4; ++j) lh[tid + j * 256] = 0;
    __syncthreads();
    int base = blockIdx.x * SC_TILE + tid * 16;
    int sv[16], dv[16];
    bool act = base < E;
    if (act) {
#pragma unroll
        for (int q = 0; q < 4; ++q) {
            *(int4*)&sv[q * 4] = *(const int4*)&src[base + q * 4];
            *(int4*)&dv[q * 4] = *(const int4*)&dst[base + q * 4];
        }
#pragma unroll
        for (int j = 0; j < 16; ++j) atomicAdd(&lh[dv[j] >> BSH], 1);
    }
    __syncthreads();
#pragma unroll
    for (int j = 0; j < 4; ++j) {
        int idx = tid + j * 256;
        int c = lh[idx];
        if (c > 0) lcur[idx] = atomicAdd(&bcursor[idx], c);
    }
    __syncthreads();
    if (act) {
#pragma unroll
        for (int j = 0; j < 16; ++j) {
            int b = dv[j] >> BSH;
            int pos = atomicAdd(&lcur[b], 1);
            staging[pos] = (unsigned int)sv[j] | ((unsigned int)(dv[j] & DLOWM) << 16);
        }
    }
}

// One block per bucket. Deterministic stable LSD radix sort (6 x 4-bit) by
// key (dlow<<16 | src) -> ssrc bit-deterministic regardless of scatter order.
#define SORT_CAP 2048
#define MIDX(f) ((f) + ((f) >> 4))
__global__ __launch_bounds__(256) void bucket_sort_kernel(const unsigned int* __restrict__ staging,
                                                          const int* __restrict__ bbase,
                                                          int* __restrict__ offsets,
                                                          int* __restrict__ ssrc, int N) {
    __shared__ unsigned int bufA[SORT_CAP];
    __shared__ unsigned int bufB[SORT_CAP];
    __shared__ int mat[4096 + 256];
    __shared__ int lh[64];
    __shared__ int wsum[4];
    int b = blockIdx.x;
    int tid = threadIdx.x;
    int s = bbase[b], e = bbase[b + 1];
    int cnt = e - s;
    bool fits = cnt <= SORT_CAP;

    if (tid < 64) lh[tid] = 0;
    __syncthreads();
    if (fits) {
        for (int i = tid; i < cnt; i += 256) {
            unsigned int r = staging[s + i];
            bufA[i] = r;
            atomicAdd(&lh[r >> 16], 1);
        }
    } else {
        for (int i = tid; i < cnt; i += 256) atomicAdd(&lh[staging[s + i] >> 16], 1);
    }
    __syncthreads();

    int exc0 = 0;
    if (tid < 64) {
        int own = lh[tid];
        int v = own;
#pragma unroll
        for (int off = 1; off < 64; off <<= 1) {
            int u = __shfl_up(v, off);
            if (tid >= off) v += u;
        }
        exc0 = v - own;
        int dstn = (b << BSH) + tid;
        if (dstn < N) offsets[dstn] = s + exc0;
    }
    __syncthreads();

    int lane = tid & 63, wid = tid >> 6;
    if (fits) {
        unsigned int* in = bufA;
        unsigned int* out = bufB;
        int L = (cnt + 255) >> 8;
        int i0 = tid * L;
        int i1 = i0 + L;
        if (i0 > cnt) i0 = cnt;
        if (i1 > cnt) i1 = cnt;
        for (int sh = 0; sh < KEYBITS; sh += 4) {
            int c16[16];
#pragma unroll
            for (int d = 0; d < 16; ++d) c16[d] = 0;
            for (int i = i0; i < i1; ++i) c16[(in[i] >> sh) & 15]++;
#pragma unroll
            for (int d = 0; d < 16; ++d) mat[MIDX(d * 256 + tid)] = c16[d];
            __syncthreads();
            int base = tid * 16;
            int loc[16];
            int ssum = 0;
#pragma unroll
            for (int j = 0; j < 16; ++j) {
                loc[j] = ssum;
                ssum += mat[MIDX(base + j)];
            }
            int vv = ssum;
#pragma unroll
            for (int off = 1; off < 64; off <<= 1) {
                int u = __shfl_up(vv, off);
                if (lane >= off) vv += u;
            }
            if (lane == 63) wsum[wid] = vv;
            __syncthreads();
            int add2 = 0;
            for (int w = 0; w < wid; ++w) add2 += wsum[w];
            int exc2 = vv + add2 - ssum;
#pragma unroll
            for (int j = 0; j < 16; ++j) mat[MIDX(base + j)] = exc2 + loc[j];
            __syncthreads();
#pragma unroll
            for (int d = 0; d < 16; ++d) c16[d] = mat[MIDX(d * 256 + tid)];
            for (int i = i0; i < i1; ++i) {
                unsigned int r = in[i];
                int d = (r >> sh) & 15;
                out[c16[d]++] = r;
            }
            __syncthreads();
            unsigned int* tmp = in;
            in = out;
            out = tmp;
        }
        for (int i = tid; i < cnt; i += 256) {
            unsigned int r = bufA[i];
            int dlow = (r >> 16) & DLOWM;
            unsigned int full = (r & 0xFFFFu) | ((unsigned int)((b << BSH) | dlow) << 16);
            ssrc[s + i] = (int)full;
        }
    } else {
        if (tid < 64) lh[tid] = exc0;
        __syncthreads();
        for (int i = tid; i < cnt; i += 256) {
            unsigned int rec = staging[s + i];
            int dlow = rec >> 16;
            int r = atomicAdd(&lh[dlow], 1);
            unsigned int full = (rec & 0xFFFFu) | ((unsigned int)((b << BSH) | dlow) << 16);
            ssrc[s + r] = (int)full;
        }
    }
}

// ---------------- fp16 weight split + bcount zero ----------------

__global__ void split_w_kernel(const float* __restrict__ W0, const float* __restrict__ W1,
                               const float* __restrict__ W2, f16* __restrict__ w0h,
                               f16* __restrict__ w0l, f16* __restrict__ w1h,
                               f16* __restrict__ w1l, f16* __restrict__ w2h,
                               f16* __restrict__ w2l, int* __restrict__ bcount, int NBK) {
    int idx = blockIdx.x * 256 + threadIdx.x;
    if (idx < NBK) bcount[idx] = 0;
    if (idx < 16384) {
        int k = idx >> 7, c = idx & 127;
        float v = W0[k * 128 + c];
        f16 h = (f16)v;
        w0h[c * 128 + k] = h;
        w0l[c * 128 + k] = (f16)(v - (float)h);
    } else if (idx < 32768) {
        int t = idx - 16384;
        int k = t >> 7, c = t & 127;
        float v = W1[k * 128 + c];
        f16 h = (f16)v;
        w1h[c * 128 + k] = h;
        w1l[c * 128 + k] = (f16)(v - (float)h);
    } else if (idx < 40960) {
        int t = idx - 32768;
        int k = t >> 6, c = t & 63;
        float v = W2[k * 64 + c];
        f16 h = (f16)v;
        w2h[c * 128 + k] = h;
        w2l[c * 128 + k] = (f16)(v - (float)h);
    }
}

// ---------------- gemm0 (fp32 A, in-register split) ∥ bucket_count ----------------
__global__ __launch_bounds__(256) void gemm0_csr_kernel(
    const float* __restrict__ Af, const f16* __restrict__ Bh, const f16* __restrict__ Bl,
    const float* __restrict__ a_src, const float* __restrict__ a_dst, f16* __restrict__ H16,
    float* __restrict__ asrc, float* __restrict__ adst, int N, int gG,
    const int* __restrict__ dstarr, int E, int NBK, int* __restrict__ bcount) {
    constexpr int FOUT = 128, H_ = 4, CT = 8, TPH = 2;
    __shared__ __align__(16) char shraw[2 * FOUT * 72 * 2];  // 36864 B
    int tid = threadIdx.x;

    if (blockIdx.x < gG) {
        f16(*lw)[FOUT][72] = reinterpret_cast<f16(*)[FOUT][72]>(shraw);
        int w = tid >> 6, lane = tid & 63;
        int quad = lane >> 4, m = lane & 15;
        int row0 = blockIdx.x * 64 + w * 16;
        int arow = row0 + m;
        if (arow >= N) arow = N - 1;
        const float* apf = &Af[(size_t)arow * 128 + quad * 8];

        f32x4 acc[CT];
#pragma unroll
        for (int t = 0; t < CT; ++t) acc[t] = (f32x4){0.f, 0.f, 0.f, 0.f};

        for (int kh = 0; kh < 2; ++kh) {
            __syncthreads();
            for (int f = tid; f < FOUT * 8; f += 256) {
                int col = f >> 3, ch = f & 7;
                *(f16x8*)&lw[0][col][ch * 8] =
                    *(const f16x8*)&Bh[(size_t)col * 128 + kh * 64 + ch * 8];
                *(f16x8*)&lw[1][col][ch * 8] =
                    *(const f16x8*)&Bl[(size_t)col * 128 + kh * 64 + ch * 8];
            }
            __syncthreads();
#pragma unroll
            for (int kc = 0; kc < 2; ++kc) {
                f16x8 fah, fal;
                const float* p = apf + kh * 64 + kc * 32;
                float4 v0 = *(const float4*)p;
                float4 v1 = *(const float4*)(p + 4);
                float vv[8] = {v0.x, v0.y, v0.z, v0.w, v1.x, v1.y, v1.z, v1.w};
#pragma unroll
                for (int j = 0; j < 8; ++j) {
                    f16 h = (f16)vv[j];
                    fah[j] = h;
                    fal[j] = (f16)(vv[j] - (float)h);
                }
#pragma unroll
                for (int t = 0; t < CT; ++t) {
                    f16x8 fbh = *(const f16x8*)&lw[0][t * 16 + m][kc * 32 + quad * 8];
                    f16x8 fbl = *(const f16x8*)&lw[1][t * 16 + m][kc * 32 + quad * 8];
                    acc[t] = __builtin_amdgcn_mfma_f32_16x16x32_f16(fah, fbh, acc[t], 0, 0, 0);
                    acc[t] = __builtin_amdgcn_mfma_f32_16x16x32_f16(fal, fbh, acc[t], 0, 0, 0);
                    acc[t] = __builtin_amdgcn_mfma_f32_16x16x32_f16(fah, fbl, acc[t], 0, 0, 0);
                }
            }
        }

        float asf[CT], adf[CT];
#pragma unroll
        for (int t = 0; t < CT; ++t) {
            asf[t] = a_src[t * 16 + m];
            adf[t] = a_dst[t * 16 + m];
        }

#pragma unroll
        for (int r = 0; r < 4; ++r) {
            int row = row0 + quad * 4 + r;
            f16 hq[CT];
            float hr[CT];
#pragma unroll
            for (int t = 0; t < CT; ++t) {
                hq[t] = (f16)acc[t][r];
                hr[t] = (float)hq[t];
            }
            float pa[H_], pd[H_];
#pragma unroll
            for (int hh = 0; hh < H_; ++hh) {
                pa[hh] = 0.f;
                pd[hh] = 0.f;
#pragma unroll
                for (int tt = 0; tt < TPH; ++tt) {
                    int t = hh * TPH + tt;
                    pa[hh] += hr[t] * asf[t];
                    pd[hh] += hr[t] * adf[t];
                }
            }
#pragma unroll
            for (int mask = 1; mask < 16; mask <<= 1) {
#pragma unroll
                for (int hh = 0; hh < H_; ++hh) {
                    pa[hh] += __shfl_xor(pa[hh], mask);
                    pd[hh] += __shfl_xor(pd[hh], mask);
                }
            }
            if (row < N) {
#pragma unroll
                for (int t = 0; t < CT; ++t) H16[(size_t)row * FOUT + t * 16 + m] = hq[t];
#pragma unroll
                for (int hh = 0; hh < H_; ++hh) {
                    if (m == hh) {
                        asrc[row * H_ + hh] = pa[hh];
                        adst[row * H_ + hh] = pd[hh];
                    }
                }
            }
        }
    } else {
        // bucket_count path (no fence; kernel boundary publishes counts)
        int* lh = (int*)shraw;
#pragma unroll
        for (int j = 0; j < 4; ++j) lh[tid + j * 256] = 0;
        __syncthreads();
        int cb = blockIdx.x - gG;
        int stride = CNTB * 256 * 4;
        for (int i = (cb * 256 + tid) * 4; i < E; i += stride) {
            int4 d = *(const int4*)&dstarr[i];
            atomicAdd(&lh[d.x >> BSH], 1);
            atomicAdd(&lh[d.y >> BSH], 1);
            atomicAdd(&lh[d.z >> BSH], 1);
            atomicAdd(&lh[d.w >> BSH], 1);
        }
        __syncthreads();
#pragma unroll
        for (int j = 0; j < 4; ++j) {
            int idx = tid + j * 256;
            if (idx < NBK) {
                int v = lh[idx];
                if (v > 0) atomicAdd(&bcount[idx], v);
            }
        }
    }
}

// ---------------- split-fp16 MFMA GEMM + fused alpha (layers 1-2) ----------------
template <int FOUT, int H_>
__global__ __launch_bounds__(256) void gemm_mfma_kernel(
    const f16* __restrict__ Ah, const f16* __restrict__ Al, const f16* __restrict__ Bh,
    const f16* __restrict__ Bl, const float* __restrict__ a_src, const float* __restrict__ a_dst,
    f16* __restrict__ H16, float* __restrict__ asrc, float* __restrict__ adst, int N) {
    constexpr int CT = FOUT / 16;
    constexpr int TPH = CT / H_;
    __shared__ f16 lw[2][FOUT][72];
    int tid = threadIdx.x;
    int w = tid >> 6, lane = tid & 63;
    int quad = lane >> 4, m = lane & 15;
    int row0 = blockIdx.x * 64 + w * 16;
    int arow = row0 + m;
    if (arow >= N) arow = N - 1;
    const f16* aph = &Ah[(size_t)arow * 128 + quad * 8];
    const f16* apl = &Al[(size_t)arow * 128 + quad * 8];

    f32x4 acc[CT];
#pragma unroll
    for (int t = 0; t < CT; ++t) acc[t] = (f32x4){0.f, 0.f, 0.f, 0.f};

    for (int kh = 0; kh < 2; ++kh) {
        __syncthreads();
        for (int f = tid; f < FOUT * 8; f += 256) {
            int col = f >> 3, ch = f & 7;
            *(f16x8*)&lw[0][col][ch * 8] = *(const f16x8*)&Bh[(size_t)col * 128 + kh * 64 + ch * 8];
            *(f16x8*)&lw[1][col][ch * 8] = *(const f16x8*)&Bl[(size_t)col * 128 + kh * 64 + ch * 8];
        }
        __syncthreads();
#pragma unroll
        for (int kc = 0; kc < 2; ++kc) {
            f16x8 fah = *(const f16x8*)&aph[kh * 64 + kc * 32];
            f16x8 fal = *(const f16x8*)&apl[kh * 64 + kc * 32];
#pragma unroll
            for (int t = 0; t < CT; ++t) {
                f16x8 fbh = *(const f16x8*)&lw[0][t * 16 + m][kc * 32 + quad * 8];
                f16x8 fbl = *(const f16x8*)&lw[1][t * 16 + m][kc * 32 + quad * 8];
                acc[t] = __builtin_amdgcn_mfma_f32_16x16x32_f16(fah, fbh, acc[t], 0, 0, 0);
                acc[t] = __builtin_amdgcn_mfma_f32_16x16x32_f16(fal, fbh, acc[t], 0, 0, 0);
                acc[t] = __builtin_amdgcn_mfma_f32_16x16x32_f16(fah, fbl, acc[t], 0, 0, 0);
            }
        }
    }

    float asf[CT], adf[CT];
#pragma unroll
    for (int t = 0; t < CT; ++t) {
        asf[t] = a_src[t * 16 + m];
        adf[t] = a_dst[t * 16 + m];
    }

#pragma unroll
    for (int r = 0; r < 4; ++r) {
        int row = row0 + quad * 4 + r;
        f16 hq[CT];
        float hr[CT];
#pragma unroll
        for (int t = 0; t < CT; ++t) {
            hq[t] = (f16)acc[t][r];
            hr[t] = (float)hq[t];
        }
        float pa[H_], pd[H_];
#pragma unroll
        for (int hh = 0; hh < H_; ++hh) {
            pa[hh] = 0.f;
            pd[hh] = 0.f;
#pragma unroll
            for (int tt = 0; tt < TPH; ++tt) {
                int t = hh * TPH + tt;
                pa[hh] += hr[t] * asf[t];
                pd[hh] += hr[t] * adf[t];
            }
        }
#pragma unroll
        for (int mask = 1; mask < 16; mask <<= 1) {
#pragma unroll
            for (int hh = 0; hh < H_; ++hh) {
                pa[hh] += __shfl_xor(pa[hh], mask);
                pd[hh] += __shfl_xor(pd[hh], mask);
            }
        }
        if (row < N) {
#pragma unroll
            for (int t = 0; t < CT; ++t) H16[(size_t)row * FOUT + t * 16 + m] = hq[t];
#pragma unroll
            for (int hh = 0; hh < H_; ++hh) {
                if (m == hh) {
                    asrc[row * H_ + hh] = pa[hh];
                    adst[row * H_ + hh] = pd[hh];
                }
            }
        }
    }
}

// ---------------- aggregation: group-per-edge, deep predicated batching ----------------
// FOUT=128: 4 groups x 16 lanes, UN=8 (32 rows in flight/wave);
// FOUT=64: 8 groups x 8 lanes, UN=4. Invalid slots reload the round's first
// edge and multiply by exactly 0.0f -> bit-identical accumulation.
template <int H_, int C, bool RELU, bool SPLIT_OUT>
__global__ __launch_bounds__(256) void aggr_kernel(
    const f16* __restrict__ h16, const float* __restrict__ asrc,
    const float* __restrict__ adst, const float* __restrict__ bias,
    const int* __restrict__ offsets, const int* __restrict__ ssrc, float* __restrict__ outf,
    f16* __restrict__ outh, f16* __restrict__ outl, int N) {
    constexpr int FOUT = H_ * C;
    constexpr int LPG = FOUT / 8;
    constexpr int GROUPS = 64 / LPG;
    constexpr int UN = (GROUPS == 4) ? 8 : 4;
    int wid = threadIdx.x >> 6;
    int lane = threadIdx.x & 63;
    int n = blockIdx.x * 4 + wid;
    if (n >= N) return;
    int g = lane / LPG;
    int t = lane % LPG;
    int c0 = t * 8;
    int head = c0 / C;

    float adn = adst[n * H_ + head];
    float esf = lrelu(asrc[n * H_ + head] + adn);

    float D = 0.f;
    float S[8];
#pragma unroll
    for (int j = 0; j < 8; ++j) S[j] = 0.f;
    if (g == 0) {
        D = 1.f;
        f16x8 hv = *(const f16x8*)&h16[n * FOUT + c0];
#pragma unroll
        for (int j = 0; j < 8; ++j) S[j] = (float)hv[j];
    }

    int e1 = offsets[n + 1];
    int k = offsets[n] + g;

    for (; k < e1; k += UN * GROUPS) {
        int sarr[UN];
        bool valid[UN];
        float aval[UN];
        f16x8 hvv[UN];
#pragma unroll
        for (int u = 0; u < UN; ++u) {
            int kk = k + u * GROUPS;
            valid[u] = kk < e1;
            sarr[u] = ssrc[valid[u] ? kk : k] & 0xFFFF;
        }
#pragma unroll
        for (int u = 0; u < UN; ++u) {
            aval[u] = asrc[sarr[u] * H_ + head];
            hvv[u] = *(const f16x8*)&h16[sarr[u] * FOUT + c0];
        }
#pragma unroll
        for (int u = 0; u < UN; ++u) {
            float w = valid[u] ? __expf(lrelu(aval[u] + adn) - esf) : 0.f;
            D += w;
#pragma unroll
            for (int j = 0; j < 8; ++j) S[j] += w * (float)hvv[u][j];
        }
    }

#pragma unroll
    for (int mask = LPG; mask < 64; mask <<= 1) {
        D += __shfl_xor(D, mask);
#pragma unroll
        for (int j = 0; j < 8; ++j) S[j] += __shfl_xor(S[j], mask);
    }

    if (g == 0) {
        float inv = 1.f / (D + 1e-16f);
        float v[8];
#pragma unroll
        for (int j = 0; j < 8; ++j) {
            v[j] = S[j] * inv + bias[c0 + j];
            if (RELU) v[j] = fmaxf(v[j], 0.f);
        }
        if (SPLIT_OUT) {
            f16x8 hh, ll;
#pragma unroll
            for (int j = 0; j < 8; ++j) {
                f16 h = (f16)v[j];
                hh[j] = h;
                ll[j] = (f16)(v[j] - (float)h);
            }
            *(f16x8*)&outh[n * FOUT + c0] = hh;
            *(f16x8*)&outl[n * FOUT + c0] = ll;
        } else {
            *(float4*)&outf[n * FOUT + c0] = make_float4(v[0], v[1], v[2], v[3]);
            *(float4*)&outf[n * FOUT + c0 + 4] = make_float4(v[4], v[5], v[6], v[7]);
        }
    }
}

extern "C" void kernel_launch(void* const* d_in, const int* in_sizes, int n_in,
                              void* d_out, int out_size, void* d_ws, size_t ws_size,
                              hipStream_t stream) {
    const float* x = (const float*)d_in[0];
    const int* ei = (const int*)d_in[1];
    const float* W0 = (const float*)d_in[2];
    const float* as0 = (const float*)d_in[3];
    const float* ad0 = (const float*)d_in[4];
    const float* b0 = (const float*)d_in[5];
    const float* W1 = (const float*)d_in[6];
    const float* as1 = (const float*)d_in[7];
    const float* ad1 = (const float*)d_in[8];
    const float* b1 = (const float*)d_in[9];
    const float* W2 = (const float*)d_in[10];
    const float* as2 = (const float*)d_in[11];
    const float* ad2 = (const float*)d_in[12];
    const float* b2 = (const float*)d_in[13];

    const int N = in_sizes[0] / 128;       // 50000
    const int E = in_sizes[1] / 2;         // 800000
    const int NBK = (N + (1 << BSH) - 1) >> BSH;  // 782 coarse buckets

    // workspace carve (all 16B-aligned)
    float* aS = (float*)d_ws;                  // N*4 f32
    float* aD = aS + (size_t)N * 4;            // N*4 f32
    f16* h16 = (f16*)(aD + (size_t)N * 4);     // N*128 f16
    f16* xh = h16 + (size_t)N * 128;           // N*128 f16
    f16* xl = xh + (size_t)N * 128;            // N*128 f16
    f16* w0h = xl + (size_t)N * 128;           // 128*128
    f16* w0l = w0h + 16384;
    f16* w1h = w0l + 16384;
    f16* w1l = w1h + 16384;
    f16* w2h = w1l + 16384;                    // 64*128
    f16* w2l = w2h + 8192;
    int* offsets = (int*)(w2l + 8192);         // N+1
    int* ssrc = offsets + N + 1;               // E (packed src|dst<<16)
    unsigned int* staging = (unsigned int*)(ssrc + E);  // E
    int* bcount = (int*)(staging + E);         // NBK
    int* bbase = bcount + NBK;                 // NBK+1
    int* bcursor = bbase + NBK + 1;            // NBK

    const int gGemm = (N + 63) / 64;           // 782
    const int gAggr = (N + 3) / 4;

    // ---- K1: weight split + bcount zero ----
    split_w_kernel<<<160, 256, 0, stream>>>(W0, W1, W2, w0h, w0l, w1h, w1l, w2h, w2l,
                                            bcount, NBK);
    // ---- K2: gemm0 ∥ bucket_count ----
    gemm0_csr_kernel<<<gGemm + CNTB, 256, 0, stream>>>(x, w0h, w0l, as0, ad0, h16, aS, aD, N,
                                                       gGemm, ei + E, E, NBK, bcount);
    // ---- K3..K5: scan + scatter + sort ----
    bucket_scan_kernel<<<1, 256, 0, stream>>>(bcount, NBK, bbase, bcursor, offsets, N);
    bucket_scatter_kernel<<<(E + SC_TILE - 1) / SC_TILE, 256, 0, stream>>>(ei, ei + E, E, bcursor,
                                                                           staging);
    bucket_sort_kernel<<<NBK, 256, 0, stream>>>(staging, bbase, offsets, ssrc, N);

    // ---- layer 0 aggregation ----
    aggr_kernel<4, 32, true, true><<<gAggr, 256, 0, stream>>>(h16, aS, aD, b0, offsets, ssrc,
                                                              nullptr, xh, xl, N);
    // ---- layer 1 ----
    gemm_mfma_kernel<128, 4><<<gGemm, 256, 0, stream>>>(xh, xl, w1h, w1l, as1, ad1, h16, aS, aD, N);
    aggr_kernel<4, 32, true, true><<<gAggr, 256, 0, stream>>>(h16, aS, aD, b1, offsets, ssrc,
                                                              nullptr, xh, xl, N);
    // ---- layer 2 ----
    gemm_mfma_kernel<64, 1><<<gGemm, 256, 0, stream>>>(xh, xl, w2h, w2l, as2, ad2, h16, aS, aD, N);
    aggr_kernel<1, 64, false, false><<<gAggr, 256, 0, stream>>>(h16, aS, aD, b2, offsets, ssrc,
                                                                (float*)d_out, nullptr, nullptr,
                                                                N);
}

// Round 17
// 291.298 us; speedup vs baseline: 1.0213x; 1.0213x over previous
//
#include <hip/hip_runtime.h>

// GAT encoder, 3 layers. N=50000, E=800000, Fin=128.
// R16 -> R17: REVERT to R15 exactly (best known: 292.3 us). R16's UN=8
// cost 12 VGPRs -> occupancy 65%->51% -> lost more TLP latency-hiding than
// the extra per-wave MLP gained (same failure mode as R11). UN=4 (FOUT=128)
// / UN=2 (FOUT=64) with predicated batching is the empirical optimum.

#define NEG_SLOPE 0.2f

typedef _Float16 f16;
typedef f16 f16x8 __attribute__((ext_vector_type(8)));
typedef f16 f16x4 __attribute__((ext_vector_type(4)));
typedef f16 f16x2 __attribute__((ext_vector_type(2)));
typedef float f32x4 __attribute__((ext_vector_type(4)));

#define BSH 6                    // coarse bucket = dst >> BSH
#define DLOWM 63                 // dlow mask (6 bits)
#define KEYBITS 22               // 6-bit dlow + 16-bit src
#define CNTB 196                 // count blocks appended to gemm0

__device__ __forceinline__ float lrelu(float v) { return v > 0.f ? v : NEG_SLOPE * v; }

// ---------------- CSR build pieces ----------------

// Exclusive scan of NBK bucket counts; seeds bcursor; offsets[N]=E.
__global__ __launch_bounds__(256) void bucket_scan_kernel(const int* __restrict__ bcount, int NBK,
                                                          int* __restrict__ bbase,
                                                          int* __restrict__ bcursor,
                                                          int* __restrict__ offsets, int N) {
    int t = threadIdx.x;
    int chunk = (NBK + 255) / 256;
    int b0 = t * chunk, b1 = b0 + chunk;
    if (b0 > NBK) b0 = NBK;
    if (b1 > NBK) b1 = NBK;
    int s = 0;
    for (int i = b0; i < b1; ++i) s += bcount[i];
    int v = s;
    int lane = t & 63, wid = t >> 6;
#pragma unroll
    for (int off = 1; off < 64; off <<= 1) {
        int u = __shfl_up(v, off);
        if (lane >= off) v += u;
    }
    __shared__ int ws[4];
    if (lane == 63) ws[wid] = v;
    __syncthreads();
    int add = 0;
    for (int w = 0; w < wid; ++w) add += ws[w];
    v += add;
    int prefix = v - s;
    for (int i = b0; i < b1; ++i) {
        bbase[i] = prefix;
        bcursor[i] = prefix;
        prefix += bcount[i];
    }
    if (t == 255) {
        bbase[NBK] = v;
        offsets[N] = v;
    }
}

#define SC_TILE 4096
__global__ __launch_bounds__(256) void bucket_scatter_kernel(const int* __restrict__ src,
                                                             const int* __restrict__ dst, int E,
                                                             int* __restrict__ bcursor,
                                                             unsigned int* __restrict__ staging) {
    __shared__ int lh[1024];
    __shared__ int lcur[1024];
    int tid = threadIdx.x;
#pragma unroll
    for (int j = 0; j < 4; ++j) lh[tid + j * 256] = 0;
    __syncthreads();
    int base = blockIdx.x * SC_TILE + tid * 16;
    int sv[16], dv[16];
    bool act = base < E;
    if (act) {
#pragma unroll
        for (int q = 0; q < 4; ++q) {
            *(int4*)&sv[q * 4] = *(const int4*)&src[base + q * 4];
            *(int4*)&dv[q * 4] = *(const int4*)&dst[base + q * 4];
        }
#pragma unroll
        for (int j = 0; j < 16; ++j) atomicAdd(&lh[dv[j] >> BSH], 1);
    }
    __syncthreads();
#pragma unroll
    for (int j = 0; j < 4; ++j) {
        int idx = tid + j * 256;
        int c = lh[idx];
        if (c > 0) lcur[idx] = atomicAdd(&bcursor[idx], c);
    }
    __syncthreads();
    if (act) {
#pragma unroll
        for (int j = 0; j < 16; ++j) {
            int b = dv[j] >> BSH;
            int pos = atomicAdd(&lcur[b], 1);
            staging[pos] = (unsigned int)sv[j] | ((unsigned int)(dv[j] & DLOWM) << 16);
        }
    }
}

// One block per bucket. Deterministic stable LSD radix sort (6 x 4-bit) by
// key (dlow<<16 | src) -> ssrc bit-deterministic regardless of scatter order.
#define SORT_CAP 2048
#define MIDX(f) ((f) + ((f) >> 4))
__global__ __launch_bounds__(256) void bucket_sort_kernel(const unsigned int* __restrict__ staging,
                                                          const int* __restrict__ bbase,
                                                          int* __restrict__ offsets,
                                                          int* __restrict__ ssrc, int N) {
    __shared__ unsigned int bufA[SORT_CAP];
    __shared__ unsigned int bufB[SORT_CAP];
    __shared__ int mat[4096 + 256];
    __shared__ int lh[64];
    __shared__ int wsum[4];
    int b = blockIdx.x;
    int tid = threadIdx.x;
    int s = bbase[b], e = bbase[b + 1];
    int cnt = e - s;
    bool fits = cnt <= SORT_CAP;

    if (tid < 64) lh[tid] = 0;
    __syncthreads();
    if (fits) {
        for (int i = tid; i < cnt; i += 256) {
            unsigned int r = staging[s + i];
            bufA[i] = r;
            atomicAdd(&lh[r >> 16], 1);
        }
    } else {
        for (int i = tid; i < cnt; i += 256) atomicAdd(&lh[staging[s + i] >> 16], 1);
    }
    __syncthreads();

    int exc0 = 0;
    if (tid < 64) {
        int own = lh[tid];
        int v = own;
#pragma unroll
        for (int off = 1; off < 64; off <<= 1) {
            int u = __shfl_up(v, off);
            if (tid >= off) v += u;
        }
        exc0 = v - own;
        int dstn = (b << BSH) + tid;
        if (dstn < N) offsets[dstn] = s + exc0;
    }
    __syncthreads();

    int lane = tid & 63, wid = tid >> 6;
    if (fits) {
        unsigned int* in = bufA;
        unsigned int* out = bufB;
        int L = (cnt + 255) >> 8;
        int i0 = tid * L;
        int i1 = i0 + L;
        if (i0 > cnt) i0 = cnt;
        if (i1 > cnt) i1 = cnt;
        for (int sh = 0; sh < KEYBITS; sh += 4) {
            int c16[16];
#pragma unroll
            for (int d = 0; d < 16; ++d) c16[d] = 0;
            for (int i = i0; i < i1; ++i) c16[(in[i] >> sh) & 15]++;
#pragma unroll
            for (int d = 0; d < 16; ++d) mat[MIDX(d * 256 + tid)] = c16[d];
            __syncthreads();
            int base = tid * 16;
            int loc[16];
            int ssum = 0;
#pragma unroll
            for (int j = 0; j < 16; ++j) {
                loc[j] = ssum;
                ssum += mat[MIDX(base + j)];
            }
            int vv = ssum;
#pragma unroll
            for (int off = 1; off < 64; off <<= 1) {
                int u = __shfl_up(vv, off);
                if (lane >= off) vv += u;
            }
            if (lane == 63) wsum[wid] = vv;
            __syncthreads();
            int add2 = 0;
            for (int w = 0; w < wid; ++w) add2 += wsum[w];
            int exc2 = vv + add2 - ssum;
#pragma unroll
            for (int j = 0; j < 16; ++j) mat[MIDX(base + j)] = exc2 + loc[j];
            __syncthreads();
#pragma unroll
            for (int d = 0; d < 16; ++d) c16[d] = mat[MIDX(d * 256 + tid)];
            for (int i = i0; i < i1; ++i) {
                unsigned int r = in[i];
                int d = (r >> sh) & 15;
                out[c16[d]++] = r;
            }
            __syncthreads();
            unsigned int* tmp = in;
            in = out;
            out = tmp;
        }
        for (int i = tid; i < cnt; i += 256) {
            unsigned int r = bufA[i];
            int dlow = (r >> 16) & DLOWM;
            unsigned int full = (r & 0xFFFFu) | ((unsigned int)((b << BSH) | dlow) << 16);
            ssrc[s + i] = (int)full;
        }
    } else {
        if (tid < 64) lh[tid] = exc0;
        __syncthreads();
        for (int i = tid; i < cnt; i += 256) {
            unsigned int rec = staging[s + i];
            int dlow = rec >> 16;
            int r = atomicAdd(&lh[dlow], 1);
            unsigned int full = (rec & 0xFFFFu) | ((unsigned int)((b << BSH) | dlow) << 16);
            ssrc[s + r] = (int)full;
        }
    }
}

// ---------------- fp16 weight split + bcount zero ----------------

__global__ void split_w_kernel(const float* __restrict__ W0, const float* __restrict__ W1,
                               const float* __restrict__ W2, f16* __restrict__ w0h,
                               f16* __restrict__ w0l, f16* __restrict__ w1h,
                               f16* __restrict__ w1l, f16* __restrict__ w2h,
                               f16* __restrict__ w2l, int* __restrict__ bcount, int NBK) {
    int idx = blockIdx.x * 256 + threadIdx.x;
    if (idx < NBK) bcount[idx] = 0;
    if (idx < 16384) {
        int k = idx >> 7, c = idx & 127;
        float v = W0[k * 128 + c];
        f16 h = (f16)v;
        w0h[c * 128 + k] = h;
        w0l[c * 128 + k] = (f16)(v - (float)h);
    } else if (idx < 32768) {
        int t = idx - 16384;
        int k = t >> 7, c = t & 127;
        float v = W1[k * 128 + c];
        f16 h = (f16)v;
        w1h[c * 128 + k] = h;
        w1l[c * 128 + k] = (f16)(v - (float)h);
    } else if (idx < 40960) {
        int t = idx - 32768;
        int k = t >> 6, c = t & 63;
        float v = W2[k * 64 + c];
        f16 h = (f16)v;
        w2h[c * 128 + k] = h;
        w2l[c * 128 + k] = (f16)(v - (float)h);
    }
}

// ---------------- gemm0 (fp32 A, in-register split) ∥ bucket_count ----------------
__global__ __launch_bounds__(256) void gemm0_csr_kernel(
    const float* __restrict__ Af, const f16* __restrict__ Bh, const f16* __restrict__ Bl,
    const float* __restrict__ a_src, const float* __restrict__ a_dst, f16* __restrict__ H16,
    float* __restrict__ asrc, float* __restrict__ adst, int N, int gG,
    const int* __restrict__ dstarr, int E, int NBK, int* __restrict__ bcount) {
    constexpr int FOUT = 128, H_ = 4, CT = 8, TPH = 2;
    __shared__ __align__(16) char shraw[2 * FOUT * 72 * 2];  // 36864 B
    int tid = threadIdx.x;

    if (blockIdx.x < gG) {
        f16(*lw)[FOUT][72] = reinterpret_cast<f16(*)[FOUT][72]>(shraw);
        int w = tid >> 6, lane = tid & 63;
        int quad = lane >> 4, m = lane & 15;
        int row0 = blockIdx.x * 64 + w * 16;
        int arow = row0 + m;
        if (arow >= N) arow = N - 1;
        const float* apf = &Af[(size_t)arow * 128 + quad * 8];

        f32x4 acc[CT];
#pragma unroll
        for (int t = 0; t < CT; ++t) acc[t] = (f32x4){0.f, 0.f, 0.f, 0.f};

        for (int kh = 0; kh < 2; ++kh) {
            __syncthreads();
            for (int f = tid; f < FOUT * 8; f += 256) {
                int col = f >> 3, ch = f & 7;
                *(f16x8*)&lw[0][col][ch * 8] =
                    *(const f16x8*)&Bh[(size_t)col * 128 + kh * 64 + ch * 8];
                *(f16x8*)&lw[1][col][ch * 8] =
                    *(const f16x8*)&Bl[(size_t)col * 128 + kh * 64 + ch * 8];
            }
            __syncthreads();
#pragma unroll
            for (int kc = 0; kc < 2; ++kc) {
                f16x8 fah, fal;
                const float* p = apf + kh * 64 + kc * 32;
                float4 v0 = *(const float4*)p;
                float4 v1 = *(const float4*)(p + 4);
                float vv[8] = {v0.x, v0.y, v0.z, v0.w, v1.x, v1.y, v1.z, v1.w};
#pragma unroll
                for (int j = 0; j < 8; ++j) {
                    f16 h = (f16)vv[j];
                    fah[j] = h;
                    fal[j] = (f16)(vv[j] - (float)h);
                }
#pragma unroll
                for (int t = 0; t < CT; ++t) {
                    f16x8 fbh = *(const f16x8*)&lw[0][t * 16 + m][kc * 32 + quad * 8];
                    f16x8 fbl = *(const f16x8*)&lw[1][t * 16 + m][kc * 32 + quad * 8];
                    acc[t] = __builtin_amdgcn_mfma_f32_16x16x32_f16(fah, fbh, acc[t], 0, 0, 0);
                    acc[t] = __builtin_amdgcn_mfma_f32_16x16x32_f16(fal, fbh, acc[t], 0, 0, 0);
                    acc[t] = __builtin_amdgcn_mfma_f32_16x16x32_f16(fah, fbl, acc[t], 0, 0, 0);
                }
            }
        }

        float asf[CT], adf[CT];
#pragma unroll
        for (int t = 0; t < CT; ++t) {
            asf[t] = a_src[t * 16 + m];
            adf[t] = a_dst[t * 16 + m];
        }

#pragma unroll
        for (int r = 0; r < 4; ++r) {
            int row = row0 + quad * 4 + r;
            f16 hq[CT];
            float hr[CT];
#pragma unroll
            for (int t = 0; t < CT; ++t) {
                hq[t] = (f16)acc[t][r];
                hr[t] = (float)hq[t];
            }
            float pa[H_], pd[H_];
#pragma unroll
            for (int hh = 0; hh < H_; ++hh) {
                pa[hh] = 0.f;
                pd[hh] = 0.f;
#pragma unroll
                for (int tt = 0; tt < TPH; ++tt) {
                    int t = hh * TPH + tt;
                    pa[hh] += hr[t] * asf[t];
                    pd[hh] += hr[t] * adf[t];
                }
            }
#pragma unroll
            for (int mask = 1; mask < 16; mask <<= 1) {
#pragma unroll
                for (int hh = 0; hh < H_; ++hh) {
                    pa[hh] += __shfl_xor(pa[hh], mask);
                    pd[hh] += __shfl_xor(pd[hh], mask);
                }
            }
            if (row < N) {
#pragma unroll
                for (int t = 0; t < CT; ++t) H16[(size_t)row * FOUT + t * 16 + m] = hq[t];
#pragma unroll
                for (int hh = 0; hh < H_; ++hh) {
                    if (m == hh) {
                        asrc[row * H_ + hh] = pa[hh];
                        adst[row * H_ + hh] = pd[hh];
                    }
                }
            }
        }
    } else {
        // bucket_count path (no fence; kernel boundary publishes counts)
        int* lh = (int*)shraw;
#pragma unroll
        for (int j = 0; j < 4; ++j) lh[tid + j * 256] = 0;
        __syncthreads();
        int cb = blockIdx.x - gG;
        int stride = CNTB * 256 * 4;
        for (int i = (cb * 256 + tid) * 4; i < E; i += stride) {
            int4 d = *(const int4*)&dstarr[i];
            atomicAdd(&lh[d.x >> BSH], 1);
            atomicAdd(&lh[d.y >> BSH], 1);
            atomicAdd(&lh[d.z >> BSH], 1);
            atomicAdd(&lh[d.w >> BSH], 1);
        }
        __syncthreads();
#pragma unroll
        for (int j = 0; j < 4; ++j) {
            int idx = tid + j * 256;
            if (idx < NBK) {
                int v = lh[idx];
                if (v > 0) atomicAdd(&bcount[idx], v);
            }
        }
    }
}

// ---------------- split-fp16 MFMA GEMM + fused alpha (layers 1-2) ----------------
template <int FOUT, int H_>
__global__ __launch_bounds__(256) void gemm_mfma_kernel(
    const f16* __restrict__ Ah, const f16* __restrict__ Al, const f16* __restrict__ Bh,
    const f16* __restrict__ Bl, const float* __restrict__ a_src, const float* __restrict__ a_dst,
    f16* __restrict__ H16, float* __restrict__ asrc, float* __restrict__ adst, int N) {
    constexpr int CT = FOUT / 16;
    constexpr int TPH = CT / H_;
    __shared__ f16 lw[2][FOUT][72];
    int tid = threadIdx.x;
    int w = tid >> 6, lane = tid & 63;
    int quad = lane >> 4, m = lane & 15;
    int row0 = blockIdx.x * 64 + w * 16;
    int arow = row0 + m;
    if (arow >= N) arow = N - 1;
    const f16* aph = &Ah[(size_t)arow * 128 + quad * 8];
    const f16* apl = &Al[(size_t)arow * 128 + quad * 8];

    f32x4 acc[CT];
#pragma unroll
    for (int t = 0; t < CT; ++t) acc[t] = (f32x4){0.f, 0.f, 0.f, 0.f};

    for (int kh = 0; kh < 2; ++kh) {
        __syncthreads();
        for (int f = tid; f < FOUT * 8; f += 256) {
            int col = f >> 3, ch = f & 7;
            *(f16x8*)&lw[0][col][ch * 8] = *(const f16x8*)&Bh[(size_t)col * 128 + kh * 64 + ch * 8];
            *(f16x8*)&lw[1][col][ch * 8] = *(const f16x8*)&Bl[(size_t)col * 128 + kh * 64 + ch * 8];
        }
        __syncthreads();
#pragma unroll
        for (int kc = 0; kc < 2; ++kc) {
            f16x8 fah = *(const f16x8*)&aph[kh * 64 + kc * 32];
            f16x8 fal = *(const f16x8*)&apl[kh * 64 + kc * 32];
#pragma unroll
            for (int t = 0; t < CT; ++t) {
                f16x8 fbh = *(const f16x8*)&lw[0][t * 16 + m][kc * 32 + quad * 8];
                f16x8 fbl = *(const f16x8*)&lw[1][t * 16 + m][kc * 32 + quad * 8];
                acc[t] = __builtin_amdgcn_mfma_f32_16x16x32_f16(fah, fbh, acc[t], 0, 0, 0);
                acc[t] = __builtin_amdgcn_mfma_f32_16x16x32_f16(fal, fbh, acc[t], 0, 0, 0);
                acc[t] = __builtin_amdgcn_mfma_f32_16x16x32_f16(fah, fbl, acc[t], 0, 0, 0);
            }
        }
    }

    float asf[CT], adf[CT];
#pragma unroll
    for (int t = 0; t < CT; ++t) {
        asf[t] = a_src[t * 16 + m];
        adf[t] = a_dst[t * 16 + m];
    }

#pragma unroll
    for (int r = 0; r < 4; ++r) {
        int row = row0 + quad * 4 + r;
        f16 hq[CT];
        float hr[CT];
#pragma unroll
        for (int t = 0; t < CT; ++t) {
            hq[t] = (f16)acc[t][r];
            hr[t] = (float)hq[t];
        }
        float pa[H_], pd[H_];
#pragma unroll
        for (int hh = 0; hh < H_; ++hh) {
            pa[hh] = 0.f;
            pd[hh] = 0.f;
#pragma unroll
            for (int tt = 0; tt < TPH; ++tt) {
                int t = hh * TPH + tt;
                pa[hh] += hr[t] * asf[t];
                pd[hh] += hr[t] * adf[t];
            }
        }
#pragma unroll
        for (int mask = 1; mask < 16; mask <<= 1) {
#pragma unroll
            for (int hh = 0; hh < H_; ++hh) {
                pa[hh] += __shfl_xor(pa[hh], mask);
                pd[hh] += __shfl_xor(pd[hh], mask);
            }
        }
        if (row < N) {
#pragma unroll
            for (int t = 0; t < CT; ++t) H16[(size_t)row * FOUT + t * 16 + m] = hq[t];
#pragma unroll
            for (int hh = 0; hh < H_; ++hh) {
                if (m == hh) {
                    asrc[row * H_ + hh] = pa[hh];
                    adst[row * H_ + hh] = pd[hh];
                }
            }
        }
    }
}

// ---------------- aggregation: group-per-edge, predicated batched rounds ----------------
// FOUT=128: 4 groups x 16 lanes, UN=4; FOUT=64: 8 groups x 8 lanes, UN=2.
// Invalid slots reload the round's first edge (L2-hot) and contribute w=0
// (exact no-op) -> bit-identical accumulation.
template <int H_, int C, bool RELU, bool SPLIT_OUT>
__global__ __launch_bounds__(256) void aggr_kernel(
    const f16* __restrict__ h16, const float* __restrict__ asrc,
    const float* __restrict__ adst, const float* __restrict__ bias,
    const int* __restrict__ offsets, const int* __restrict__ ssrc, float* __restrict__ outf,
    f16* __restrict__ outh, f16* __restrict__ outl, int N) {
    constexpr int FOUT = H_ * C;
    constexpr int LPG = FOUT / 8;
    constexpr int GROUPS = 64 / LPG;
    constexpr int UN = (GROUPS == 4) ? 4 : 2;
    int wid = threadIdx.x >> 6;
    int lane = threadIdx.x & 63;
    int n = blockIdx.x * 4 + wid;
    if (n >= N) return;
    int g = lane / LPG;
    int t = lane % LPG;
    int c0 = t * 8;
    int head = c0 / C;

    float adn = adst[n * H_ + head];
    float esf = lrelu(asrc[n * H_ + head] + adn);

    float D = 0.f;
    float S[8];
#pragma unroll
    for (int j = 0; j < 8; ++j) S[j] = 0.f;
    if (g == 0) {
        D = 1.f;
        f16x8 hv = *(const f16x8*)&h16[n * FOUT + c0];
#pragma unroll
        for (int j = 0; j < 8; ++j) S[j] = (float)hv[j];
    }

    int e1 = offsets[n + 1];
    int k = offsets[n] + g;

    for (; k < e1; k += UN * GROUPS) {
        int sarr[UN];
        bool valid[UN];
        float aval[UN];
        f16x8 hvv[UN];
#pragma unroll
        for (int u = 0; u < UN; ++u) {
            int kk = k + u * GROUPS;
            valid[u] = kk < e1;
            sarr[u] = ssrc[valid[u] ? kk : k] & 0xFFFF;
        }
#pragma unroll
        for (int u = 0; u < UN; ++u) {
            aval[u] = asrc[sarr[u] * H_ + head];
            hvv[u] = *(const f16x8*)&h16[sarr[u] * FOUT + c0];
        }
#pragma unroll
        for (int u = 0; u < UN; ++u) {
            float w = valid[u] ? __expf(lrelu(aval[u] + adn) - esf) : 0.f;
            D += w;
#pragma unroll
            for (int j = 0; j < 8; ++j) S[j] += w * (float)hvv[u][j];
        }
    }

#pragma unroll
    for (int mask = LPG; mask < 64; mask <<= 1) {
        D += __shfl_xor(D, mask);
#pragma unroll
        for (int j = 0; j < 8; ++j) S[j] += __shfl_xor(S[j], mask);
    }

    if (g == 0) {
        float inv = 1.f / (D + 1e-16f);
        float v[8];
#pragma unroll
        for (int j = 0; j < 8; ++j) {
            v[j] = S[j] * inv + bias[c0 + j];
            if (RELU) v[j] = fmaxf(v[j], 0.f);
        }
        if (SPLIT_OUT) {
            f16x8 hh, ll;
#pragma unroll
            for (int j = 0; j < 8; ++j) {
                f16 h = (f16)v[j];
                hh[j] = h;
                ll[j] = (f16)(v[j] - (float)h);
            }
            *(f16x8*)&outh[n * FOUT + c0] = hh;
            *(f16x8*)&outl[n * FOUT + c0] = ll;
        } else {
            *(float4*)&outf[n * FOUT + c0] = make_float4(v[0], v[1], v[2], v[3]);
            *(float4*)&outf[n * FOUT + c0 + 4] = make_float4(v[4], v[5], v[6], v[7]);
        }
    }
}

extern "C" void kernel_launch(void* const* d_in, const int* in_sizes, int n_in,
                              void* d_out, int out_size, void* d_ws, size_t ws_size,
                              hipStream_t stream) {
    const float* x = (const float*)d_in[0];
    const int* ei = (const int*)d_in[1];
    const float* W0 = (const float*)d_in[2];
    const float* as0 = (const float*)d_in[3];
    const float* ad0 = (const float*)d_in[4];
    const float* b0 = (const float*)d_in[5];
    const float* W1 = (const float*)d_in[6];
    const float* as1 = (const float*)d_in[7];
    const float* ad1 = (const float*)d_in[8];
    const float* b1 = (const float*)d_in[9];
    const float* W2 = (const float*)d_in[10];
    const float* as2 = (const float*)d_in[11];
    const float* ad2 = (const float*)d_in[12];
    const float* b2 = (const float*)d_in[13];

    const int N = in_sizes[0] / 128;       // 50000
    const int E = in_sizes[1] / 2;         // 800000
    const int NBK = (N + (1 << BSH) - 1) >> BSH;  // 782 coarse buckets

    // workspace carve (all 16B-aligned)
    float* aS = (float*)d_ws;                  // N*4 f32
    float* aD = aS + (size_t)N * 4;            // N*4 f32
    f16* h16 = (f16*)(aD + (size_t)N * 4);     // N*128 f16
    f16* xh = h16 + (size_t)N * 128;           // N*128 f16
    f16* xl = xh + (size_t)N * 128;            // N*128 f16
    f16* w0h = xl + (size_t)N * 128;           // 128*128
    f16* w0l = w0h + 16384;
    f16* w1h = w0l + 16384;
    f16* w1l = w1h + 16384;
    f16* w2h = w1l + 16384;                    // 64*128
    f16* w2l = w2h + 8192;
    int* offsets = (int*)(w2l + 8192);         // N+1
    int* ssrc = offsets + N + 1;               // E (packed src|dst<<16)
    unsigned int* staging = (unsigned int*)(ssrc + E);  // E
    int* bcount = (int*)(staging + E);         // NBK
    int* bbase = bcount + NBK;                 // NBK+1
    int* bcursor = bbase + NBK + 1;            // NBK

    const int gGemm = (N + 63) / 64;           // 782
    const int gAggr = (N + 3) / 4;

    // ---- K1: weight split + bcount zero ----
    split_w_kernel<<<160, 256, 0, stream>>>(W0, W1, W2, w0h, w0l, w1h, w1l, w2h, w2l,
                                            bcount, NBK);
    // ---- K2: gemm0 ∥ bucket_count ----
    gemm0_csr_kernel<<<gGemm + CNTB, 256, 0, stream>>>(x, w0h, w0l, as0, ad0, h16, aS, aD, N,
                                                       gGemm, ei + E, E, NBK, bcount);
    // ---- K3..K5: scan + scatter + sort ----
    bucket_scan_kernel<<<1, 256, 0, stream>>>(bcount, NBK, bbase, bcursor, offsets, N);
    bucket_scatter_kernel<<<(E + SC_TILE - 1) / SC_TILE, 256, 0, stream>>>(ei, ei + E, E, bcursor,
                                                                           staging);
    bucket_sort_kernel<<<NBK, 256, 0, stream>>>(staging, bbase, offsets, ssrc, N);

    // ---- layer 0 aggregation ----
    aggr_kernel<4, 32, true, true><<<gAggr, 256, 0, stream>>>(h16, aS, aD, b0, offsets, ssrc,
                                                              nullptr, xh, xl, N);
    // ---- layer 1 ----
    gemm_mfma_kernel<128, 4><<<gGemm, 256, 0, stream>>>(xh, xl, w1h, w1l, as1, ad1, h16, aS, aD, N);
    aggr_kernel<4, 32, true, true><<<gAggr, 256, 0, stream>>>(h16, aS, aD, b1, offsets, ssrc,
                                                              nullptr, xh, xl, N);
    // ---- layer 2 ----
    gemm_mfma_kernel<64, 1><<<gGemm, 256, 0, stream>>>(xh, xl, w2h, w2l, as2, ad2, h16, aS, aD, N);
    aggr_kernel<1, 64, false, false><<<gAggr, 256, 0, stream>>>(h16, aS, aD, b2, offsets, ssrc,
                                                                (float*)d_out, nullptr, nullptr,
                                                                N);
}